// Round 1
// baseline (755.782 us; speedup 1.0000x reference)
//
#include <hip/hip_runtime.h>
#include <math.h>

typedef __attribute__((ext_vector_type(8))) short short8;
typedef __attribute__((ext_vector_type(4))) float f32x4;
typedef __attribute__((ext_vector_type(4))) unsigned short us4;
typedef __attribute__((ext_vector_type(4))) float fl4;

#define B_ 2
#define S_ 2048
#define H_ 16
#define D_ 128
#define HID 2048
#define M_ (B_*S_)

__device__ __forceinline__ unsigned short f2bf(float f){
  unsigned u = __builtin_bit_cast(unsigned, f);
  u += 0x7fffu + ((u >> 16) & 1u);
  return (unsigned short)(u >> 16);
}
__device__ __forceinline__ float bf2f(unsigned short u){
  unsigned x = ((unsigned)u) << 16;
  return __builtin_bit_cast(float, x);
}

// ---------- f32 -> bf16 convert (4 elems/thread) ----------
__global__ void cvt_k(const float* __restrict__ src, unsigned short* __restrict__ dst){
  int i = (blockIdx.x * 256 + threadIdx.x) * 4;
  fl4 v = *(const fl4*)(src + i);
  us4 o;
  #pragma unroll
  for (int t = 0; t < 4; t++) o[t] = f2bf(v[t]);
  *(us4*)(dst + i) = o;
}

// ---------- cos/sin tables from freqs ----------
__global__ void tab_k(const float* __restrict__ freqs, float* __restrict__ ctab,
                      float* __restrict__ stab){
  int i = blockIdx.x * 256 + threadIdx.x;
  float f = freqs[i];
  ctab[i] = cosf(f);
  stab[i] = sinf(f);
}

// ---------- GEMM: C[i][j] = sum_k A[i][k] * W[j][k]  (A,W bf16 row-major) ----------
// EPI==1: z in {0,1,2} picks W/out; writes bf16 scattered to [B,H,S,D]
// EPI==0: writes f32 to Of[i*2048 + j]
template<int EPI>
__global__ __launch_bounds__(256) void gemm_k(
    const unsigned short* __restrict__ A,
    const unsigned short* __restrict__ W0,
    const unsigned short* __restrict__ W1,
    const unsigned short* __restrict__ W2,
    unsigned short* __restrict__ O0,
    unsigned short* __restrict__ O1,
    unsigned short* __restrict__ O2,
    float* __restrict__ Of)
{
  __shared__ __align__(16) unsigned short As[128 * 32];
  __shared__ __align__(16) unsigned short Bs[128 * 32];
  const int tid = threadIdx.x;
  const int w = tid >> 6, l = tid & 63, lg = l >> 4, lr = l & 15;
  const int m0 = blockIdx.x * 128, n0 = blockIdx.y * 128;
  const unsigned short* Bm;
  if (EPI == 1) Bm = blockIdx.z == 0 ? W0 : (blockIdx.z == 1 ? W1 : W2);
  else          Bm = W0;

  f32x4 acc[4][4];
  #pragma unroll
  for (int i = 0; i < 4; i++)
    #pragma unroll
    for (int j = 0; j < 4; j++)
      acc[i][j] = f32x4{0.f, 0.f, 0.f, 0.f};

  const int wm = w & 1, wn = w >> 1;
  const int sr = tid >> 2, sc = (tid & 3) * 8;   // staging: row, col8

  for (int kt = 0; kt < HID; kt += 32){
    // global loads for this K-step (overlap with previous compute)
    short8 a0 = *(const short8*)(A  + (size_t)(m0 +      sr) * HID + kt + sc);
    short8 a1 = *(const short8*)(A  + (size_t)(m0 + 64 + sr) * HID + kt + sc);
    short8 b0 = *(const short8*)(Bm + (size_t)(n0 +      sr) * HID + kt + sc);
    short8 b1 = *(const short8*)(Bm + (size_t)(n0 + 64 + sr) * HID + kt + sc);
    __syncthreads();                 // previous iter's LDS reads complete
    *(short8*)(As + sr * 32 + sc)        = a0;
    *(short8*)(As + (64 + sr) * 32 + sc) = a1;
    *(short8*)(Bs + sr * 32 + sc)        = b0;
    *(short8*)(Bs + (64 + sr) * 32 + sc) = b1;
    __syncthreads();

    short8 aF[4], bF[4];
    #pragma unroll
    for (int mi = 0; mi < 4; mi++)
      aF[mi] = *(const short8*)(As + (wm * 64 + mi * 16 + lr) * 32 + lg * 8);
    #pragma unroll
    for (int ni = 0; ni < 4; ni++)
      bF[ni] = *(const short8*)(Bs + (wn * 64 + ni * 16 + lr) * 32 + lg * 8);
    #pragma unroll
    for (int mi = 0; mi < 4; mi++)
      #pragma unroll
      for (int ni = 0; ni < 4; ni++)
        acc[mi][ni] = __builtin_amdgcn_mfma_f32_16x16x32_bf16(aF[mi], bF[ni], acc[mi][ni], 0, 0, 0);
  }

  if (EPI == 1){
    unsigned short* O = blockIdx.z == 0 ? O0 : (blockIdx.z == 1 ? O1 : O2);
    #pragma unroll
    for (int mi = 0; mi < 4; mi++){
      #pragma unroll
      for (int r = 0; r < 4; r++){
        int i = m0 + wm * 64 + mi * 16 + lg * 4 + r;
        int b = i >> 11, s = i & 2047;
        #pragma unroll
        for (int ni = 0; ni < 4; ni++){
          int j = n0 + wn * 64 + ni * 16 + lr;
          int h = j >> 7, d = j & 127;
          O[((size_t)(b * H_ + h) * S_ + s) * D_ + d] = f2bf(acc[mi][ni][r]);
        }
      }
    }
  } else {
    #pragma unroll
    for (int mi = 0; mi < 4; mi++)
      #pragma unroll
      for (int r = 0; r < 4; r++){
        int i = m0 + wm * 64 + mi * 16 + lg * 4 + r;
        #pragma unroll
        for (int ni = 0; ni < 4; ni++){
          int j = n0 + wn * 64 + ni * 16 + lr;
          Of[(size_t)i * HID + j] = acc[mi][ni][r];
        }
      }
  }
}

// ---------- in-place RoPE on Q and K ([B,H,S,D] bf16) ----------
__global__ void rope_k(unsigned short* __restrict__ Q, unsigned short* __restrict__ K,
                       const float* __restrict__ ctab, const float* __restrict__ stab){
  int idx = blockIdx.x * 256 + threadIdx.x;          // 2 * 2^20 threads
  unsigned short* P = (idx >= (1 << 20)) ? K : Q;
  int e  = idx & ((1 << 20) - 1);
  int g  = e & 15;
  int s  = (e >> 4) & 2047;
  int bh = e >> 15;
  int d0 = g * 4;
  size_t base = ((size_t)bh * S_ + s) * D_;
  us4 qa = *(us4*)(P + base + d0);
  us4 qb = *(us4*)(P + base + d0 + 64);
  fl4 ca = *(const fl4*)(ctab + s * D_ + d0);
  fl4 sa = *(const fl4*)(stab + s * D_ + d0);
  fl4 cb = *(const fl4*)(ctab + s * D_ + d0 + 64);
  fl4 sb = *(const fl4*)(stab + s * D_ + d0 + 64);
  us4 oa, ob;
  #pragma unroll
  for (int t = 0; t < 4; t++){
    float xa = bf2f(qa[t]), xb = bf2f(qb[t]);
    oa[t] = f2bf(xa * ca[t] - xb * sa[t]);
    ob[t] = f2bf(xb * cb[t] + xa * sb[t]);
  }
  *(us4*)(P + base + d0)      = oa;
  *(us4*)(P + base + d0 + 64) = ob;
}

// ---------- flash attention: per (b,h), 4 waves x 16 q-rows, KBLK=32 ----------
__global__ __launch_bounds__(256) void attn_k(
    const unsigned short* __restrict__ Q,     // [B,H,S,D] bf16 (rope'd)
    const unsigned short* __restrict__ Kt,    // [B,H,S,D] bf16 (rope'd)
    const unsigned short* __restrict__ V,     // [B,H,S,D] bf16
    const float* __restrict__ mask,           // [S,S]
    const float* __restrict__ alibi,          // [H,S]
    unsigned short* __restrict__ Ctx)         // [B,S,H,D] bf16
{
  __shared__ __align__(16) unsigned short Kl[32 * 128];
  __shared__ __align__(16) unsigned short Vt[128 * 32];   // transposed V tile
  __shared__ __align__(16) unsigned short Pl[4 * 16 * 32];
  const int tid = threadIdx.x;
  const int w = tid >> 6, l = tid & 63, lg = l >> 4, lr = l & 15;
  const int bh = blockIdx.y, b = bh >> 4, h = bh & 15;
  const int q0 = blockIdx.x * 64 + w * 16;
  const size_t hb = (size_t)bh * S_ * D_;

  short8 qf[4];
  #pragma unroll
  for (int c = 0; c < 4; c++)
    qf[c] = *(const short8*)(Q + hb + (size_t)(q0 + lr) * D_ + c * 32 + lg * 8);

  f32x4 acc[8];
  #pragma unroll
  for (int c = 0; c < 8; c++) acc[c] = f32x4{0.f, 0.f, 0.f, 0.f};
  float mrow[4] = {-3e38f, -3e38f, -3e38f, -3e38f};
  float lsum[4] = {0.f, 0.f, 0.f, 0.f};
  const float scale = 0.08838834764831845f;   // 1/sqrt(128)
  const float* al = alibi + h * S_;

  const int kr = tid >> 4, kc = (tid & 15) * 8;     // K staging
  const int vrow = tid >> 3, vcol = (tid & 7) * 16; // V staging (16 elems/thread)

  for (int t = 0; t < 64; t++){
    const int kv0 = t * 32;
    short8 k0 = *(const short8*)(Kt + hb + (size_t)(kv0 + kr)      * D_ + kc);
    short8 k1 = *(const short8*)(Kt + hb + (size_t)(kv0 + 16 + kr) * D_ + kc);
    short8 v0 = *(const short8*)(V  + hb + (size_t)(kv0 + vrow)    * D_ + vcol);
    short8 v1 = *(const short8*)(V  + hb + (size_t)(kv0 + vrow)    * D_ + vcol + 8);
    __syncthreads();                 // previous iter's LDS reads complete
    *(short8*)(Kl + kr * D_ + kc)        = k0;
    *(short8*)(Kl + (16 + kr) * D_ + kc) = k1;
    #pragma unroll
    for (int e = 0; e < 8; e++){
      Vt[(vcol + e) * 32 + vrow]     = (unsigned short)v0[e];
      Vt[(vcol + 8 + e) * 32 + vrow] = (unsigned short)v1[e];
    }
    __syncthreads();

    // S = Q K^T for 2 key-halves of 16
    f32x4 sv0 = f32x4{0.f, 0.f, 0.f, 0.f}, sv1 = sv0;
    #pragma unroll
    for (int c = 0; c < 4; c++){
      short8 kf = *(const short8*)(Kl + lr * D_ + c * 32 + lg * 8);
      sv0 = __builtin_amdgcn_mfma_f32_16x16x32_bf16(qf[c], kf, sv0, 0, 0, 0);
    }
    #pragma unroll
    for (int c = 0; c < 4; c++){
      short8 kf = *(const short8*)(Kl + (16 + lr) * D_ + c * 32 + lg * 8);
      sv1 = __builtin_amdgcn_mfma_f32_16x16x32_bf16(qf[c], kf, sv1, 0, 0, 0);
    }

    float a0 = al[kv0 + lr], a1 = al[kv0 + 16 + lr];
    #pragma unroll
    for (int r = 0; r < 4; r++){
      const int qg = q0 + lg * 4 + r;
      float x0 = sv0[r] * scale + mask[(size_t)qg * S_ + kv0 + lr]      + a0;
      float x1 = sv1[r] * scale + mask[(size_t)qg * S_ + kv0 + 16 + lr] + a1;
      float tm = fmaxf(x0, x1);
      tm = fmaxf(tm, __shfl_xor(tm, 1));
      tm = fmaxf(tm, __shfl_xor(tm, 2));
      tm = fmaxf(tm, __shfl_xor(tm, 4));
      tm = fmaxf(tm, __shfl_xor(tm, 8));
      float mnew  = fmaxf(mrow[r], tm);
      float alpha = expf(mrow[r] - mnew);
      float p0 = expf(x0 - mnew);
      float p1 = expf(x1 - mnew);
      float ps = p0 + p1;
      ps += __shfl_xor(ps, 1);
      ps += __shfl_xor(ps, 2);
      ps += __shfl_xor(ps, 4);
      ps += __shfl_xor(ps, 8);
      lsum[r] = lsum[r] * alpha + ps;
      mrow[r] = mnew;
      #pragma unroll
      for (int c = 0; c < 8; c++) acc[c][r] *= alpha;
      Pl[w * 512 + (lg * 4 + r) * 32 + lr]      = f2bf(p0);
      Pl[w * 512 + (lg * 4 + r) * 32 + 16 + lr] = f2bf(p1);
    }

    // PV: acc[c] += P(16x32) * V(32x16-chunk c)
    short8 pf = *(const short8*)(Pl + w * 512 + lr * 32 + lg * 8);
    #pragma unroll
    for (int c = 0; c < 8; c++){
      short8 vf = *(const short8*)(Vt + (c * 16 + lr) * 32 + lg * 8);
      acc[c] = __builtin_amdgcn_mfma_f32_16x16x32_bf16(pf, vf, acc[c], 0, 0, 0);
    }
  }

  #pragma unroll
  for (int r = 0; r < 4; r++){
    const int qg = q0 + lg * 4 + r;
    const float inv = 1.0f / lsum[r];
    const size_t ob = ((size_t)(b * S_ + qg) * H_ + h) * D_;
    #pragma unroll
    for (int c = 0; c < 8; c++)
      Ctx[ob + c * 16 + lr] = f2bf(acc[c][r] * inv);
  }
}

extern "C" void kernel_launch(void* const* d_in, const int* in_sizes, int n_in,
                              void* d_out, int out_size, void* d_ws, size_t ws_size,
                              hipStream_t stream){
  const float* x     = (const float*)d_in[0];
  const float* mask  = (const float*)d_in[1];
  const float* alibi = (const float*)d_in[2];
  const float* freqs = (const float*)d_in[3];
  const float* Wq    = (const float*)d_in[4];
  const float* Wk    = (const float*)d_in[5];
  const float* Wv    = (const float*)d_in[6];
  const float* Wo    = (const float*)d_in[7];
  float* out = (float*)d_out;

  unsigned short* ws  = (unsigned short*)d_ws;
  unsigned short* xb  = ws;                    // 8388608 elems (reused as ctx)
  unsigned short* wqb = ws + 8388608;          // 4194304
  unsigned short* wkb = ws + 12582912;
  unsigned short* wvb = ws + 16777216;
  unsigned short* wob = ws + 20971520;
  unsigned short* Qb  = ws + 25165824;         // 8388608 each
  unsigned short* Kb  = ws + 33554432;
  unsigned short* Vb  = ws + 41943040;
  unsigned short* ctx = xb;                    // alias: x consumed after proj
  float* ctab = (float*)(ws + 50331648);       // 262144 floats
  float* stab = ctab + 262144;

  cvt_k<<<8192, 256, 0, stream>>>(x,  xb);
  cvt_k<<<4096, 256, 0, stream>>>(Wq, wqb);
  cvt_k<<<4096, 256, 0, stream>>>(Wk, wkb);
  cvt_k<<<4096, 256, 0, stream>>>(Wv, wvb);
  cvt_k<<<4096, 256, 0, stream>>>(Wo, wob);
  tab_k<<<1024, 256, 0, stream>>>(freqs, ctab, stab);

  gemm_k<1><<<dim3(32, 16, 3), 256, 0, stream>>>(xb, wqb, wkb, wvb, Qb, Kb, Vb, nullptr);
  rope_k<<<8192, 256, 0, stream>>>(Qb, Kb, ctab, stab);
  attn_k<<<dim3(32, 32), 256, 0, stream>>>(Qb, Kb, Vb, mask, alibi, ctx);
  gemm_k<0><<<dim3(32, 16, 1), 256, 0, stream>>>(ctx, wob, nullptr, nullptr,
                                                 nullptr, nullptr, nullptr, out);
}